// Round 9
// baseline (32.267 us; speedup 1.0000x reference)
//
#include <hip/hip_runtime.h>

#define BB 16384
#define LL 200
#define DD 100
#define VV 100000

// Kernel 1 (R3-proven, ~5.6-6.5us, HBM-BW-bound): rowdot[v] = sum_d E[v,d]*w[d].
// Half-wave (32 lanes) per row, lanes 0..24 load one float4 (25 x 16B = row).
__global__ __launch_bounds__(256) void rowdot_kernel(const float4* __restrict__ E4,
                                                     const float4* __restrict__ w4,
                                                     float* __restrict__ rowdot) {
    const int tid  = blockIdx.x * blockDim.x + threadIdx.x;
    const int wave = tid >> 6;
    const int lane = threadIdx.x & 63;
    const int half = lane >> 5;
    const int sub  = lane & 31;

    float4 wv = make_float4(0.f, 0.f, 0.f, 0.f);
    if (sub < 25) wv = w4[sub];

    const int r = wave * 2 + half;
    float s = 0.0f;
    if (sub < 25) {
        float4 v = E4[(size_t)r * 25 + sub];
        s = v.x * wv.x + v.y * wv.y + v.z * wv.z + v.w * wv.w;
    }
    #pragma unroll
    for (int off = 16; off > 0; off >>= 1)
        s += __shfl_xor(s, off, 64);
    if (sub == 0) rowdot[r] = s;
}

// Kernel 2: out[b] = (1/L) * sum_l rowdot[idx[b,l]].  FOUR ROWS PER WAVE.
// Lanes 0..49 preload one int4 per row (pf[4] = 16 indices), then all 16
// independent L2-resident gathers are issued back-to-back -> ~5x more lines
// in flight per CU than the 1-row/wave version (latency-bound regime).
__global__ __launch_bounds__(256) void pool_kernel(const int4* __restrict__ idx4,
                                                   const float* __restrict__ rowdot,
                                                   float* __restrict__ out) {
    const int tid  = blockIdx.x * blockDim.x + threadIdx.x;
    const int wave = tid >> 6;          // 0..4095
    const int lane = threadIdx.x & 63;
    const int b0   = wave * 4;
    const bool act = lane < 50;

    // preload all indices first (coalesced int4 loads)
    int4 pf[4];
    #pragma unroll
    for (int r = 0; r < 4; ++r)
        pf[r] = act ? idx4[(size_t)(b0 + r) * 50 + lane]
                    : make_int4(0, 0, 0, 0);

    // issue all 16 gathers before any use (compiler keeps them in flight)
    float g[16];
    #pragma unroll
    for (int r = 0; r < 4; ++r) {
        g[4 * r + 0] = rowdot[pf[r].x];
        g[4 * r + 1] = rowdot[pf[r].y];
        g[4 * r + 2] = rowdot[pf[r].z];
        g[4 * r + 3] = rowdot[pf[r].w];
    }

    float s[4];
    #pragma unroll
    for (int r = 0; r < 4; ++r) {
        float v = (g[4 * r] + g[4 * r + 1]) + (g[4 * r + 2] + g[4 * r + 3]);
        s[r] = act ? v : 0.0f;
        #pragma unroll
        for (int off = 32; off > 0; off >>= 1)
            s[r] += __shfl_xor(s[r], off, 64);
    }
    if (lane == 0) {
        #pragma unroll
        for (int r = 0; r < 4; ++r)
            out[b0 + r] = s[r] * (1.0f / LL);
    }
}

extern "C" void kernel_launch(void* const* d_in, const int* in_sizes, int n_in,
                              void* d_out, int out_size, void* d_ws, size_t ws_size,
                              hipStream_t stream) {
    const int4*   idx4   = (const int4*)d_in[0];      // [B, L] int32 as int4
    const float4* E4     = (const float4*)d_in[1];    // [V, D] f32 as float4
    const float4* w4     = (const float4*)d_in[2];    // [D, 1] f32 as float4
    float*        out    = (float*)d_out;             // [B, 1] f32
    float*        rowdot = (float*)d_ws;              // 400 KB scratch

    // 100000 rows, 2 rows/wave, 4 waves/block -> 12500 blocks
    rowdot_kernel<<<VV / 8, 256, 0, stream>>>(E4, w4, rowdot);
    // 16384 rows, 4 rows/wave, 4 waves/block -> 1024 blocks
    pool_kernel<<<BB / 16, 256, 0, stream>>>(idx4, rowdot, out);
}

// Round 10
// 31.140 us; speedup vs baseline: 1.0362x; 1.0362x over previous
//
#include <hip/hip_runtime.h>

#define BB 16384
#define LL 200
#define DD 100
#define VV 100000
#define NPAIR (VV / 2)     // 50000 row-pairs
#define NBLK  2048         // 8 blocks/CU -> fully co-resident, short launch ramp
#define NWAVE (NBLK * 4)   // 8192 waves = 32 waves/CU = device capacity

// Kernel 1: rowdot[v] = sum_d E[v,d]*w[d].  PERSISTENT grid-stride version.
// Half-wave (32 lanes) per row; lanes 0..24 load one float4 (25 x 16B = row).
// 2048 blocks; each wave walks ~6-7 row-pairs so the next iteration's loads
// overlap the current shfl-reduce.
__global__ __launch_bounds__(256) void rowdot_kernel(const float4* __restrict__ E4,
                                                     const float4* __restrict__ w4,
                                                     float* __restrict__ rowdot) {
    const int tid  = blockIdx.x * blockDim.x + threadIdx.x;
    const int wave = tid >> 6;
    const int lane = threadIdx.x & 63;
    const int half = lane >> 5;
    const int sub  = lane & 31;

    float4 wv = make_float4(0.f, 0.f, 0.f, 0.f);
    if (sub < 25) wv = w4[sub];

    #pragma unroll 2
    for (int p = wave; p < NPAIR; p += NWAVE) {
        const int r = p * 2 + half;
        float s = 0.0f;
        if (sub < 25) {
            float4 v = E4[(size_t)r * 25 + sub];
            s = v.x * wv.x + v.y * wv.y + v.z * wv.z + v.w * wv.w;
        }
        #pragma unroll
        for (int off = 16; off > 0; off >>= 1)
            s += __shfl_xor(s, off, 64);
        if (sub == 0) rowdot[r] = s;
    }
}

// Kernel 2: out[b] = (1/L) * sum_l rowdot[idx[b,l]].  TWO ROWS PER WAVE at
// full occupancy: 8192 waves (32/CU cap, R3's TLP) x 8 gathers in flight
// (2x R3's MLP). Lanes 0..49 load one int4 per row.
__global__ __launch_bounds__(256) void pool_kernel(const int4* __restrict__ idx4,
                                                   const float* __restrict__ rowdot,
                                                   float* __restrict__ out) {
    const int tid  = blockIdx.x * blockDim.x + threadIdx.x;
    const int wave = tid >> 6;          // 0..8191
    const int lane = threadIdx.x & 63;
    const int b0   = wave * 2;
    const bool act = lane < 50;

    int4 i0 = make_int4(0, 0, 0, 0), i1 = make_int4(0, 0, 0, 0);
    if (act) {
        i0 = idx4[(size_t)b0 * 50 + lane];
        i1 = idx4[(size_t)(b0 + 1) * 50 + lane];
    }

    // 8 independent L2-resident gathers issued back-to-back
    float g0 = rowdot[i0.x], g1 = rowdot[i0.y];
    float g2 = rowdot[i0.z], g3 = rowdot[i0.w];
    float h0 = rowdot[i1.x], h1 = rowdot[i1.y];
    float h2 = rowdot[i1.z], h3 = rowdot[i1.w];

    float s0 = act ? (g0 + g1) + (g2 + g3) : 0.0f;
    float s1 = act ? (h0 + h1) + (h2 + h3) : 0.0f;
    #pragma unroll
    for (int off = 32; off > 0; off >>= 1) {
        s0 += __shfl_xor(s0, off, 64);
        s1 += __shfl_xor(s1, off, 64);
    }
    if (lane == 0) {
        out[b0]     = s0 * (1.0f / LL);
        out[b0 + 1] = s1 * (1.0f / LL);
    }
}

extern "C" void kernel_launch(void* const* d_in, const int* in_sizes, int n_in,
                              void* d_out, int out_size, void* d_ws, size_t ws_size,
                              hipStream_t stream) {
    const int4*   idx4   = (const int4*)d_in[0];      // [B, L] int32 as int4
    const float4* E4     = (const float4*)d_in[1];    // [V, D] f32 as float4
    const float4* w4     = (const float4*)d_in[2];    // [D, 1] f32 as float4
    float*        out    = (float*)d_out;             // [B, 1] f32
    float*        rowdot = (float*)d_ws;              // 400 KB scratch

    rowdot_kernel<<<NBLK, 256, 0, stream>>>(E4, w4, rowdot);   // 2048 blocks
    pool_kernel<<<NBLK, 256, 0, stream>>>(idx4, rowdot, out);  // 2048 blocks
}

// Round 11
// 26.338 us; speedup vs baseline: 1.2251x; 1.1824x over previous
//
#include <hip/hip_runtime.h>
#include <hip/hip_fp16.h>

#define BB 16384
#define LL 200
#define DD 100
#define VV 100000
#define CHUNK  50000           // f16 entries per LDS chunk: 100,000 B
#define NCHUNK 2               // 2 * 50000 = 100000 = VV exactly
#define PBLK   128             // pool blocks (1/CU due to 100KB LDS)
#define PTHR   1024            // 16 waves/block
#define RPW    8               // rows per wave: 128 rows/block / 16 waves

// Kernel 1 (R3-proven shape): rowdot[v] = sum_d E[v,d]*w[d], stored as f16.
// Half-wave (32 lanes) per row, lanes 0..24 load one float4 (25 x 16B = row).
// f16 is safe: |rowdot| <~ 25, eps 2^-11 -> worst-case pooled err ~0.012 << 0.0316.
__global__ __launch_bounds__(256) void rowdot_kernel(const float4* __restrict__ E4,
                                                     const float4* __restrict__ w4,
                                                     __half* __restrict__ rowdot) {
    const int tid  = blockIdx.x * blockDim.x + threadIdx.x;
    const int wave = tid >> 6;
    const int lane = threadIdx.x & 63;
    const int half = lane >> 5;
    const int sub  = lane & 31;

    float4 wv = make_float4(0.f, 0.f, 0.f, 0.f);
    if (sub < 25) wv = w4[sub];

    const int r = wave * 2 + half;
    float s = 0.0f;
    if (sub < 25) {
        float4 v = E4[(size_t)r * 25 + sub];
        s = v.x * wv.x + v.y * wv.y + v.z * wv.z + v.w * wv.w;
    }
    #pragma unroll
    for (int off = 16; off > 0; off >>= 1)
        s += __shfl_xor(s, off, 64);
    if (sub == 0) rowdot[r] = __float2half(s);
}

// Kernel 2: LDS-staged f16 gather. 128 blocks x 1024 threads, 128 rows/block,
// 8 rows/wave; lanes 0..49 hold each row's indices (8 x int4) in registers.
// 2 passes: stage 100KB of the f16 table into LDS (coalesced int4), barrier,
// predicated in-range accumulate from LDS, barrier.
// Staging total = 128 blocks x 200KB = 25.6MB from L3 (4x less than R8's f32/256).
__global__ __launch_bounds__(1024) void pool_kernel(const int4* __restrict__ idx4,
                                                    const __half* __restrict__ rowdot,
                                                    float* __restrict__ out) {
    __shared__ __half sh[CHUNK];
    const int t    = threadIdx.x;
    const int wave = t >> 6;                 // 0..15
    const int lane = t & 63;
    const int row0 = blockIdx.x * (PTHR / 64 * RPW) + wave * RPW;
    const bool act = lane < 50;

    // preload indices: 8 rows x (50 lanes x int4) — read once, held in regs
    int4 pf[RPW];
    #pragma unroll
    for (int r = 0; r < RPW; ++r)
        pf[r] = act ? idx4[(size_t)(row0 + r) * 50 + lane]
                    : make_int4(0, 0, 0, 0);

    float acc[RPW];
    #pragma unroll
    for (int r = 0; r < RPW; ++r) acc[r] = 0.f;

    #pragma unroll 1
    for (int c = 0; c < NCHUNK; ++c) {
        const int base = c * CHUNK;
        __syncthreads();   // previous chunk's readers done before overwrite
        // stage CHUNK f16 = 6250 int4; 1024 threads -> 7 masked iters
        #pragma unroll 1
        for (int k = t; k < CHUNK * 2 / 16; k += PTHR)
            ((int4*)sh)[k] = ((const int4*)(rowdot))[base * 2 / 16 + k];
        __syncthreads();
        if (act) {
            #pragma unroll
            for (int r = 0; r < RPW; ++r) {
                int4 i4 = pf[r];
                int a0 = i4.x - base, a1 = i4.y - base;
                int a2 = i4.z - base, a3 = i4.w - base;
                if ((unsigned)a0 < (unsigned)CHUNK) acc[r] += __half2float(sh[a0]);
                if ((unsigned)a1 < (unsigned)CHUNK) acc[r] += __half2float(sh[a1]);
                if ((unsigned)a2 < (unsigned)CHUNK) acc[r] += __half2float(sh[a2]);
                if ((unsigned)a3 < (unsigned)CHUNK) acc[r] += __half2float(sh[a3]);
            }
        }
    }

    #pragma unroll
    for (int r = 0; r < RPW; ++r) {
        float s = acc[r];
        #pragma unroll
        for (int off = 32; off > 0; off >>= 1)
            s += __shfl_xor(s, off, 64);
        if (lane == 0) out[row0 + r] = s * (1.0f / LL);
    }
}

extern "C" void kernel_launch(void* const* d_in, const int* in_sizes, int n_in,
                              void* d_out, int out_size, void* d_ws, size_t ws_size,
                              hipStream_t stream) {
    const int4*   idx4   = (const int4*)d_in[0];      // [B, L] int32 as int4
    const float4* E4     = (const float4*)d_in[1];    // [V, D] f32 as float4
    const float4* w4     = (const float4*)d_in[2];    // [D, 1] f32 as float4
    float*        out    = (float*)d_out;             // [B, 1] f32
    __half*       rowdot = (__half*)d_ws;             // 200 KB f16 table

    // 100000 rows, 2 rows/wave, 4 waves/block -> 12500 blocks
    rowdot_kernel<<<VV / 8, 256, 0, stream>>>(E4, w4, rowdot);
    // 16384 rows / 128 rows per block -> 128 blocks of 1024 threads
    pool_kernel<<<PBLK, PTHR, 0, stream>>>(idx4, rowdot, out);
}

// Round 12
// 23.604 us; speedup vs baseline: 1.3670x; 1.1158x over previous
//
#include <hip/hip_runtime.h>
#include <hip/hip_fp16.h>

#define BB 16384
#define LL 200
#define DD 100
#define VV 100000
#define CHUNK  50000           // f16 entries per LDS chunk: 100,000 B
#define NCHUNK 2               // 2 * 50000 = 100000 = VV exactly
#define PBLK   256             // pool blocks: 1/CU (100KB LDS), ALL 256 CUs
#define PTHR   1024            // 16 waves/block
#define RPW    4               // rows per wave: 64 rows/block / 16 waves

// Kernel 1 (R3-proven shape): rowdot[v] = sum_d E[v,d]*w[d], stored as f16.
// Half-wave (32 lanes) per row, lanes 0..24 load one float4 (25 x 16B = row).
// f16 safe: |rowdot| <~ 25, eps 2^-11 -> pooled err ~0.012 << 0.0316 threshold.
__global__ __launch_bounds__(256) void rowdot_kernel(const float4* __restrict__ E4,
                                                     const float4* __restrict__ w4,
                                                     __half* __restrict__ rowdot) {
    const int tid  = blockIdx.x * blockDim.x + threadIdx.x;
    const int wave = tid >> 6;
    const int lane = threadIdx.x & 63;
    const int half = lane >> 5;
    const int sub  = lane & 31;

    float4 wv = make_float4(0.f, 0.f, 0.f, 0.f);
    if (sub < 25) wv = w4[sub];

    const int r = wave * 2 + half;
    float s = 0.0f;
    if (sub < 25) {
        float4 v = E4[(size_t)r * 25 + sub];
        s = v.x * wv.x + v.y * wv.y + v.z * wv.z + v.w * wv.w;
    }
    #pragma unroll
    for (int off = 16; off > 0; off >>= 1)
        s += __shfl_xor(s, off, 64);
    if (sub == 0) rowdot[r] = __float2half(s);
}

// Kernel 2: LDS-staged f16 gather. 256 blocks x 1024 threads, 64 rows/block
// (4 rows/wave); lanes 0..49 hold each row's indices (4 x int4) in registers.
// 2 passes: stage 100KB of the f16 table into LDS (coalesced int4), barrier,
// predicated in-range accumulate from LDS, barrier. All 256 CUs active
// (R11 used 128 blocks -> half the machine idle; probe work/CU now halved).
__global__ __launch_bounds__(1024) void pool_kernel(const int4* __restrict__ idx4,
                                                    const __half* __restrict__ rowdot,
                                                    float* __restrict__ out) {
    __shared__ __half sh[CHUNK];
    const int t    = threadIdx.x;
    const int wave = t >> 6;                 // 0..15
    const int lane = t & 63;
    const int row0 = blockIdx.x * (PTHR / 64 * RPW) + wave * RPW;
    const bool act = lane < 50;

    // preload indices first (coalesced int4, overlaps the staging below)
    int4 pf[RPW];
    #pragma unroll
    for (int r = 0; r < RPW; ++r)
        pf[r] = act ? idx4[(size_t)(row0 + r) * 50 + lane]
                    : make_int4(0, 0, 0, 0);

    float acc[RPW];
    #pragma unroll
    for (int r = 0; r < RPW; ++r) acc[r] = 0.f;

    #pragma unroll 1
    for (int c = 0; c < NCHUNK; ++c) {
        const int base = c * CHUNK;
        __syncthreads();   // previous chunk's readers done before overwrite
        // stage CHUNK f16 = 6250 int4; 1024 threads -> 7 masked iters
        #pragma unroll 1
        for (int k = t; k < CHUNK * 2 / 16; k += PTHR)
            ((int4*)sh)[k] = ((const int4*)(rowdot))[base * 2 / 16 + k];
        __syncthreads();
        if (act) {
            #pragma unroll
            for (int r = 0; r < RPW; ++r) {
                int4 i4 = pf[r];
                int a0 = i4.x - base, a1 = i4.y - base;
                int a2 = i4.z - base, a3 = i4.w - base;
                if ((unsigned)a0 < (unsigned)CHUNK) acc[r] += __half2float(sh[a0]);
                if ((unsigned)a1 < (unsigned)CHUNK) acc[r] += __half2float(sh[a1]);
                if ((unsigned)a2 < (unsigned)CHUNK) acc[r] += __half2float(sh[a2]);
                if ((unsigned)a3 < (unsigned)CHUNK) acc[r] += __half2float(sh[a3]);
            }
        }
    }

    #pragma unroll
    for (int r = 0; r < RPW; ++r) {
        float s = acc[r];
        #pragma unroll
        for (int off = 32; off > 0; off >>= 1)
            s += __shfl_xor(s, off, 64);
        if (lane == 0) out[row0 + r] = s * (1.0f / LL);
    }
}

extern "C" void kernel_launch(void* const* d_in, const int* in_sizes, int n_in,
                              void* d_out, int out_size, void* d_ws, size_t ws_size,
                              hipStream_t stream) {
    const int4*   idx4   = (const int4*)d_in[0];      // [B, L] int32 as int4
    const float4* E4     = (const float4*)d_in[1];    // [V, D] f32 as float4
    const float4* w4     = (const float4*)d_in[2];    // [D, 1] f32 as float4
    float*        out    = (float*)d_out;             // [B, 1] f32
    __half*       rowdot = (__half*)d_ws;             // 200 KB f16 table

    // 100000 rows, 2 rows/wave, 4 waves/block -> 12500 blocks
    rowdot_kernel<<<VV / 8, 256, 0, stream>>>(E4, w4, rowdot);
    // 16384 rows / 64 rows per block -> 256 blocks of 1024 threads
    pool_kernel<<<PBLK, PTHR, 0, stream>>>(idx4, rowdot, out);
}